// Round 5
// baseline (322.771 us; speedup 1.0000x reference)
//
#include <hip/hip_runtime.h>

// GPTQ W4A32 linear via bf16 MFMA, magic-mantissa dequant, fused x-staging,
// single-dispatch split-K with device-scope semaphore reduction.
// out(16,11008) = x(16,4096) @ W,  W[k][n] = s[g][n]*(w4[k][n] - z4[g][n]).
// bf16 bits (0x4380|w) == 256+2w exactly -> MFMA on raw nibbles gives
// P_raw = 256*X + 2*P per group (X = group-sum of bf16-rounded x):
// out += (s/2)*P_raw - s*(128+z)*X.  Mask-trick nibble order k={0,4,1,5,2,6,3,7}
// per 8; x staged to LDS with same permutation, XOR-swizzled (^(m&7)<<4) so
// A-frag ds_read_b128 is ~conflict-free.

#define M_DIM 16
#define K_DIM 4096
#define N_DIM 11008
#define GS 128
#define KSPLIT 16
#define KC (K_DIM / KSPLIT)      // 256 k per block chunk
#define GPC (KC / GS)            // 2 groups per chunk
#define BLOCKN 64                // 4 waves x 16 n

typedef __attribute__((ext_vector_type(8))) short short8;
typedef __attribute__((ext_vector_type(4))) float f32x4;

__device__ __forceinline__ float bfl(unsigned w) {
    union { unsigned u; float f; } c; c.u = w << 16; return c.f;
}
__device__ __forceinline__ float bfh(unsigned w) {
    union { unsigned u; float f; } c; c.u = w & 0xFFFF0000u; return c.f;
}

__global__ __launch_bounds__(256) void qlin_fused(
    const float* __restrict__ x,
    const int*   __restrict__ qweight,
    const float* __restrict__ scales,
    const int*   __restrict__ qzeros,
    float*       __restrict__ part,   // [KSPLIT][16][N] (split path)
    int*         __restrict__ cnt,    // [N/BLOCKN] semaphores (zeroed per call)
    float*       __restrict__ out,
    int nchunks)
{
    __shared__ __align__(16) unsigned short xs[M_DIM * KC];  // 8 KiB swizzled
    __shared__ __align__(16) float Xl[GPC * 16];
    __shared__ int lastf;

    const int tid  = threadIdx.x;
    const int lane = tid & 63, wave = tid >> 6;
    const int lmod = lane & 15, lhi = lane >> 4;
    const int n    = blockIdx.x * BLOCKN + wave * 16 + lmod;
    const int swzA = (lmod & 7) << 4;

    f32x4 outacc = {0.f, 0.f, 0.f, 0.f};

    for (int c = 0; c < nchunks; ++c) {
        const int ky0 = (blockIdx.y * nchunks + c) * KC;
        const int G0 = ky0 / GS, rowbase = ky0 >> 3;

        // ---- prefetch group meta + all qweight dwords (latency hides
        //      under the staging phase below)
        float    sg[GPC]; unsigned zg[GPC]; unsigned qw[GPC][4];
#pragma unroll
        for (int g = 0; g < GPC; ++g) {
            sg[g] = scales[(size_t)(G0 + g) * N_DIM + n];
            zg[g] = (unsigned)qzeros[(size_t)(G0 + g) * (N_DIM / 8) + (n >> 3)];
#pragma unroll
            for (int t = 0; t < 4; ++t)
                qw[g][t] = (unsigned)
                    qweight[(size_t)(rowbase + g * 16 + t * 4 + lhi) * N_DIM + n];
        }

        __syncthreads();   // protect xs/Xl from previous chunk
        // ---- stage x[16][KC]: f32 -> bf16 (RNE), permuted, swizzled
#pragma unroll
        for (int i = 0; i < (M_DIM * KC / 8) / 256; ++i) {   // 2 iters
            const int idx = i * 256 + tid;
            const int m  = idx >> 5;          // KC/8 == 32 chunks per row
            const int cc = idx & 31;
            const float4* xp =
                (const float4*)(x + (size_t)m * K_DIM + ky0 + cc * 8);
            const float4 v0 = xp[0], v1 = xp[1];
            union { short8 s; unsigned u[4]; } pk;
            asm("v_cvt_pk_bf16_f32 %0, %1, %2" : "=v"(pk.u[0]) : "v"(v0.x), "v"(v1.x));
            asm("v_cvt_pk_bf16_f32 %0, %1, %2" : "=v"(pk.u[1]) : "v"(v0.y), "v"(v1.y));
            asm("v_cvt_pk_bf16_f32 %0, %1, %2" : "=v"(pk.u[2]) : "v"(v0.z), "v"(v1.z));
            asm("v_cvt_pk_bf16_f32 %0, %1, %2" : "=v"(pk.u[3]) : "v"(v0.w), "v"(v1.w));
            const int byte = ((m * KC + cc * 8) * 2) ^ ((m & 7) << 4);
            *(short8*)((char*)xs + byte) = pk.s;
        }
        __syncthreads();

        // ---- X[g][m] = group-sum of staged bf16 (wave g handles group g)
        if (wave < GPC) {
            const int g = wave;
            float xv = 0.f;
#pragma unroll
            for (int q = 0; q < 4; ++q) {
                const int byte =
                    ((lmod * KC + g * GS + lhi * 32 + q * 8) * 2) ^ swzA;
                union { short8 s; unsigned u[4]; } a;
                a.s = *(const short8*)((const char*)xs + byte);
#pragma unroll
                for (int p = 0; p < 4; ++p) xv += bfl(a.u[p]) + bfh(a.u[p]);
            }
            xv += __shfl_xor(xv, 16, 64);
            xv += __shfl_xor(xv, 32, 64);
            if (lane < 16) Xl[g * 16 + lane] = xv;
        }
        __syncthreads();

        // ---- MFMA over GPC groups, all operands register/LDS resident
#pragma unroll
        for (int g = 0; g < GPC; ++g) {
            f32x4 acc = {0.f, 0.f, 0.f, 0.f};
#pragma unroll
            for (int t = 0; t < 4; ++t) {
                union { short8 v; unsigned u[4]; } b;
                const unsigned q = qw[g][t];
                b.u[0] = ( q        & 0x000F000Fu) | 0x43804380u;
                b.u[1] = ((q >> 4)  & 0x000F000Fu) | 0x43804380u;
                b.u[2] = ((q >> 8)  & 0x000F000Fu) | 0x43804380u;
                b.u[3] = ((q >> 12) & 0x000F000Fu) | 0x43804380u;
                const int byte =
                    ((lmod * KC + g * GS + t * 32 + lhi * 8) * 2) ^ swzA;
                const short8 a = *(const short8*)((const char*)xs + byte);
                acc = __builtin_amdgcn_mfma_f32_16x16x32_bf16(a, b.v, acc, 0, 0, 0);
            }
            const f32x4 x4 = *(const f32x4*)&Xl[g * 16 + lhi * 4];
            const float z  = (float)((zg[g] >> ((n & 7) * 4)) & 15u);
            const float s2 = 0.5f * sg[g];
            const float zc = -sg[g] * (128.0f + z);
#pragma unroll
            for (int r = 0; r < 4; ++r)
                outacc[r] = fmaf(s2, acc[r], fmaf(zc, x4[r], outacc[r]));
        }
    }

    if (gridDim.y == 1) {   // fallback: full K in one block, direct out
#pragma unroll
        for (int r = 0; r < 4; ++r)
            out[(size_t)(lhi * 4 + r) * N_DIM + n] = outacc[r];
        return;
    }

    // ---- split path: write partials, last block per n-strip reduces
#pragma unroll
    for (int r = 0; r < 4; ++r)
        part[(size_t)(blockIdx.y * M_DIM + lhi * 4 + r) * N_DIM + n] = outacc[r];
    __threadfence();                       // release partials (device scope)
    __syncthreads();
    if (tid == 0)
        lastf = (atomicAdd(&cnt[blockIdx.x], 1) == (int)gridDim.y - 1);
    __syncthreads();
    if (lastf) {
        __threadfence();                   // acquire others' partials
        for (int j = tid; j < M_DIM * BLOCKN; j += 256) {
            const int m = j >> 6, cc2 = j & 63;
            const int col = blockIdx.x * BLOCKN + cc2;
            float sum = 0.f;
#pragma unroll
            for (int kk = 0; kk < KSPLIT; ++kk)
                sum += part[(size_t)(kk * M_DIM + m) * N_DIM + col];
            out[(size_t)m * N_DIM + col] = sum;
        }
    }
}

extern "C" void kernel_launch(void* const* d_in, const int* in_sizes, int n_in,
                              void* d_out, int out_size, void* d_ws, size_t ws_size,
                              hipStream_t stream) {
    const float* x       = (const float*)d_in[0];
    const int*   qweight = (const int*)d_in[1];
    const float* scales  = (const float*)d_in[2];
    const int*   qzeros  = (const int*)d_in[3];
    float*       out     = (float*)d_out;

    const int    nstrips    = N_DIM / BLOCKN;                       // 172
    const size_t cnt_bytes  = ((size_t)nstrips * 4 + 255) & ~(size_t)255;
    const size_t part_bytes = (size_t)KSPLIT * M_DIM * N_DIM * sizeof(float);

    if (ws_size >= cnt_bytes + part_bytes) {
        int*   cnt  = (int*)d_ws;
        float* part = (float*)((char*)d_ws + cnt_bytes);
        hipMemsetAsync(cnt, 0, (size_t)nstrips * 4, stream);
        dim3 grid(nstrips, KSPLIT);        // (172, 16)
        qlin_fused<<<grid, 256, 0, stream>>>(x, qweight, scales, qzeros,
                                             part, cnt, out, 1);
    } else {
        dim3 grid(nstrips, 1);
        qlin_fused<<<grid, 256, 0, stream>>>(x, qweight, scales, qzeros,
                                             nullptr, nullptr, out, KSPLIT);
    }
}

// Round 6
// 17.475 us; speedup vs baseline: 18.4710x; 18.4710x over previous
//
#include <hip/hip_runtime.h>

// GPTQ W4A32 linear via bf16 MFMA, magic-mantissa dequant, fused x-staging.
// out(16,11008) = x(16,4096) @ W,  W[k][n] = s[g][n]*(w4[k][n] - z4[g][n]).
// bf16 bits (0x4380|w) == 256+2w exactly -> MFMA on raw nibbles gives
// P_raw = 256*X + 2*P per group (X = group-sum of bf16-rounded x):
// out += (s/2)*P_raw - s*(128+z)*X.  Mask-trick nibble order k={0,4,1,5,2,6,3,7}
// per 8; x staged to LDS with same permutation, XOR-swizzled (^(m&7)<<4).
// Two dispatches, NO device-scope fences (R5 lesson: per-block __threadfence
// across 2752 blocks serialized the grid -> 320 us).

#define M_DIM 16
#define K_DIM 4096
#define N_DIM 11008
#define GS 128
#define KSPLIT 16
#define KC (K_DIM / KSPLIT)      // 256 k per block chunk
#define GPC (KC / GS)            // 2 groups per chunk
#define BLOCKN 128               // 8 waves x 16 n (512 threads)
#define NTHREADS 512

typedef __attribute__((ext_vector_type(8))) short short8;
typedef __attribute__((ext_vector_type(4))) float f32x4;

__device__ __forceinline__ float bfl(unsigned w) {
    union { unsigned u; float f; } c; c.u = w << 16; return c.f;
}
__device__ __forceinline__ float bfh(unsigned w) {
    union { unsigned u; float f; } c; c.u = w & 0xFFFF0000u; return c.f;
}

__global__ __launch_bounds__(NTHREADS) void qlin_fused(
    const float* __restrict__ x,
    const int*   __restrict__ qweight,
    const float* __restrict__ scales,
    const int*   __restrict__ qzeros,
    float*       __restrict__ outp,   // partials [KSPLIT][16][N] or out [16][N]
    int nchunks)
{
    __shared__ __align__(16) unsigned short xs[M_DIM * KC];  // 8 KiB swizzled
    __shared__ __align__(16) float Xl[GPC * 16];

    const int tid  = threadIdx.x;
    const int lane = tid & 63, wave = tid >> 6;
    const int lmod = lane & 15, lhi = lane >> 4;
    const int n    = blockIdx.x * BLOCKN + wave * 16 + lmod;
    const int swzA = (lmod & 7) << 4;

    f32x4 outacc = {0.f, 0.f, 0.f, 0.f};

    for (int c = 0; c < nchunks; ++c) {
        const int ky0 = (blockIdx.y * nchunks + c) * KC;
        const int G0 = ky0 / GS, rowbase = ky0 >> 3;

        // ---- prefetch group meta + all qweight dwords for this chunk;
        //      latency hides under the staging phase below
        float    sg[GPC]; unsigned zg[GPC]; unsigned qw[GPC][4];
#pragma unroll
        for (int g = 0; g < GPC; ++g) {
            sg[g] = scales[(size_t)(G0 + g) * N_DIM + n];
            zg[g] = (unsigned)qzeros[(size_t)(G0 + g) * (N_DIM / 8) + (n >> 3)];
#pragma unroll
            for (int t = 0; t < 4; ++t)
                qw[g][t] = (unsigned)
                    qweight[(size_t)(rowbase + g * 16 + t * 4 + lhi) * N_DIM + n];
        }

        __syncthreads();   // protect xs/Xl from previous chunk
        // ---- stage x[16][KC]: f32 -> bf16 (RNE), permuted, swizzled.
        //      M_DIM*KC/8 == 512 == NTHREADS: exactly one chunk per thread.
        {
            const int m  = tid >> 5;          // KC/8 == 32 chunks per row
            const int cc = tid & 31;
            const float4* xp =
                (const float4*)(x + (size_t)m * K_DIM + ky0 + cc * 8);
            const float4 v0 = xp[0], v1 = xp[1];
            union { short8 s; unsigned u[4]; } pk;
            asm("v_cvt_pk_bf16_f32 %0, %1, %2" : "=v"(pk.u[0]) : "v"(v0.x), "v"(v1.x));
            asm("v_cvt_pk_bf16_f32 %0, %1, %2" : "=v"(pk.u[1]) : "v"(v0.y), "v"(v1.y));
            asm("v_cvt_pk_bf16_f32 %0, %1, %2" : "=v"(pk.u[2]) : "v"(v0.z), "v"(v1.z));
            asm("v_cvt_pk_bf16_f32 %0, %1, %2" : "=v"(pk.u[3]) : "v"(v0.w), "v"(v1.w));
            const int byte = ((m * KC + cc * 8) * 2) ^ ((m & 7) << 4);
            *(short8*)((char*)xs + byte) = pk.s;
        }
        __syncthreads();

        // ---- X[g][m] = group-sum of staged bf16 (wave g handles group g)
        if (wave < GPC) {
            const int g = wave;
            float xv = 0.f;
#pragma unroll
            for (int q = 0; q < 4; ++q) {
                const int byte =
                    ((lmod * KC + g * GS + lhi * 32 + q * 8) * 2) ^ swzA;
                union { short8 s; unsigned u[4]; } a;
                a.s = *(const short8*)((const char*)xs + byte);
#pragma unroll
                for (int p = 0; p < 4; ++p) xv += bfl(a.u[p]) + bfh(a.u[p]);
            }
            xv += __shfl_xor(xv, 16, 64);
            xv += __shfl_xor(xv, 32, 64);
            if (lane < 16) Xl[g * 16 + lane] = xv;
        }
        __syncthreads();

        // ---- MFMA over GPC groups, operands register/LDS resident
#pragma unroll
        for (int g = 0; g < GPC; ++g) {
            f32x4 acc = {0.f, 0.f, 0.f, 0.f};
#pragma unroll
            for (int t = 0; t < 4; ++t) {
                union { short8 v; unsigned u[4]; } b;
                const unsigned q = qw[g][t];
                b.u[0] = ( q        & 0x000F000Fu) | 0x43804380u;
                b.u[1] = ((q >> 4)  & 0x000F000Fu) | 0x43804380u;
                b.u[2] = ((q >> 8)  & 0x000F000Fu) | 0x43804380u;
                b.u[3] = ((q >> 12) & 0x000F000Fu) | 0x43804380u;
                const int byte =
                    ((lmod * KC + g * GS + t * 32 + lhi * 8) * 2) ^ swzA;
                const short8 a = *(const short8*)((const char*)xs + byte);
                acc = __builtin_amdgcn_mfma_f32_16x16x32_bf16(a, b.v, acc, 0, 0, 0);
            }
            const f32x4 x4 = *(const f32x4*)&Xl[g * 16 + lhi * 4];
            const float z  = (float)((zg[g] >> ((n & 7) * 4)) & 15u);
            const float s2 = 0.5f * sg[g];
            const float zc = -sg[g] * (128.0f + z);
#pragma unroll
            for (int r = 0; r < 4; ++r)
                outacc[r] = fmaf(s2, acc[r], fmaf(zc, x4[r], outacc[r]));
        }
    }

#pragma unroll
    for (int r = 0; r < 4; ++r)
        outp[(size_t)(blockIdx.y * M_DIM + lhi * 4 + r) * N_DIM + n] = outacc[r];
}

__global__ __launch_bounds__(256) void qlin_reduce(
    const float* __restrict__ part, float* __restrict__ out)
{
    const int i = blockIdx.x * 256 + threadIdx.x;   // over M*N
    if (i < M_DIM * N_DIM) {
        float s = 0.f;
#pragma unroll
        for (int c = 0; c < KSPLIT; ++c)
            s += part[(size_t)c * M_DIM * N_DIM + i];
        out[i] = s;
    }
}

extern "C" void kernel_launch(void* const* d_in, const int* in_sizes, int n_in,
                              void* d_out, int out_size, void* d_ws, size_t ws_size,
                              hipStream_t stream) {
    const float* x       = (const float*)d_in[0];
    const int*   qweight = (const int*)d_in[1];
    const float* scales  = (const float*)d_in[2];
    const int*   qzeros  = (const int*)d_in[3];
    float*       out     = (float*)d_out;

    const size_t part_bytes = (size_t)KSPLIT * M_DIM * N_DIM * sizeof(float);
    if (ws_size >= part_bytes) {
        float* part = (float*)d_ws;
        dim3 grid(N_DIM / BLOCKN, KSPLIT);          // (86, 16)
        qlin_fused<<<grid, NTHREADS, 0, stream>>>(x, qweight, scales, qzeros,
                                                  part, 1);
        qlin_reduce<<<(M_DIM * N_DIM + 255) / 256, 256, 0, stream>>>(part, out);
    } else {
        dim3 grid(N_DIM / BLOCKN, 1);
        qlin_fused<<<grid, NTHREADS, 0, stream>>>(x, qweight, scales, qzeros,
                                                  out, KSPLIT);
    }
}